// Round 15
// baseline (125.573 us; speedup 1.0000x reference)
//
#include <hip/hip_runtime.h>
#include <hip/hip_bf16.h>
#include <cmath>

typedef __attribute__((ext_vector_type(8))) short bf16x8;
typedef __attribute__((ext_vector_type(4))) float f32x4;

#define NXC 1024
#define NH 16
#define HD 64
#define BATCH 2
#define SEQ 2048
#define TOK (BATCH * SEQ)

// fp32 -> bf16 RNE via HW cvt (1 VALU op; same-src so half order is irrelevant)
__device__ __forceinline__ ushort f2bf(float f) {
  unsigned u;
  asm("v_cvt_pk_bf16_f32 %0, %1, %2" : "=v"(u) : "v"(f), "v"(f));
  return (ushort)u;
}

__device__ __forceinline__ void gload_lds16(const void* g, void* lds) {
  __builtin_amdgcn_global_load_lds(
      (const __attribute__((address_space(1))) void*)g,
      (__attribute__((address_space(3))) void*)lds, 16, 0, 0);
}

__device__ __forceinline__ float fast_exp2(float x) {
  float r;
  asm("v_exp_f32 %0, %1" : "=v"(r) : "v"(x));
  return r;
}

template <int CTRL>
__device__ __forceinline__ float dpp_mov(float x) {
  return __builtin_bit_cast(
      float, __builtin_amdgcn_mov_dpp(__builtin_bit_cast(int, x), CTRL, 0xF, 0xF, true));
}
// reduce across the 16 contiguous lanes of a DPP row (row_ror 1,2,4,8)
__device__ __forceinline__ float red16_max(float x) {
  x = fmaxf(x, dpp_mov<0x121>(x));
  x = fmaxf(x, dpp_mov<0x122>(x));
  x = fmaxf(x, dpp_mov<0x124>(x));
  x = fmaxf(x, dpp_mov<0x128>(x));
  return x;
}
__device__ __forceinline__ float red16_sum(float x) {
  x += dpp_mov<0x121>(x);
  x += dpp_mov<0x122>(x);
  x += dpp_mov<0x124>(x);
  x += dpp_mov<0x128>(x);
  return x;
}

// ---------------- W [K][N] fp32 -> Wt [N][K] bf16, K-block swizzled ----------------
__global__ __launch_bounds__(256) void k_transpose_w(const float* __restrict__ in,
                                                     ushort* __restrict__ out,
                                                     int Kd, int Nd) {
  __shared__ float t[32][33];
  int n0 = blockIdx.x * 32, k0 = blockIdx.y * 32;
  int tx = threadIdx.x & 31, ty = threadIdx.x >> 5;
#pragma unroll
  for (int r = 0; r < 4; ++r)
    t[tx][ty + r * 8] = in[(size_t)(k0 + ty + r * 8) * Nd + n0 + tx];
  __syncthreads();
  int nl = threadIdx.x >> 3, kq = (threadIdx.x & 7) * 4;
  ushort4 o;
  o.x = f2bf(t[nl][kq + 0]);
  o.y = f2bf(t[nl][kq + 1]);
  o.z = f2bf(t[nl][kq + 2]);
  o.w = f2bf(t[nl][kq + 3]);
  int row = n0 + nl, kk = k0 + kq;
  size_t dst = (size_t)row * Kd + (kk & ~63) + ((kk & 63) ^ ((row & 7) << 3));
  *(ushort4*)&out[dst] = o;
}

// ---------- V [b][h][s][d] -> [b][h][d][slot] (pi-permute + XOR swizzle) ----------
// slot(s,d) = ((s&15)*4 + ((s>>4)&3)) ^ ((d&7)<<3), per 64-key tile.
__global__ __launch_bounds__(256) void k_transpose_v(const ushort* __restrict__ in,
                                                     ushort* __restrict__ out) {
  __shared__ ushort t[64][33];          // [s_local][d_local]
  int bh = blockIdx.z;
  int s0 = blockIdx.x * 64, d0 = blockIdx.y * 32;
  const ushort* ip = in + (size_t)bh * SEQ * HD;
  ushort* op = out + (size_t)bh * HD * SEQ;
  int dl_in = threadIdx.x & 31, sl_in = threadIdx.x >> 5;  // 8 s-rows per pass
#pragma unroll
  for (int m = 0; m < 8; ++m)
    t[sl_in + m * 8][dl_in] = ip[(size_t)(s0 + sl_in + m * 8) * HD + d0 + dl_in];
  __syncthreads();
  int dl = threadIdx.x >> 3;            // 0..31
  int kp = threadIdx.x & 7;             // 0..7 -> two k values
#pragma unroll
  for (int kk = 0; kk < 2; ++kk) {
    int k = kp * 2 + kk;                // 0..15
    ushort4 o;
    o.x = t[k][dl]; o.y = t[k + 16][dl]; o.z = t[k + 32][dl]; o.w = t[k + 48][dl];
    int slot = (4 * k) ^ ((dl & 7) << 3);
    *(ushort4*)&op[(size_t)(d0 + dl) * SEQ + s0 + slot] = o;
  }
}

// ---------------- QKV GEMM (fused fp32->bf16 on A): C = X * Wt^T + b ----------------
__global__ __launch_bounds__(256, 3) void k_gemm_qkv(const float* __restrict__ X,
                                                     const ushort* __restrict__ Bt,
                                                     const float* __restrict__ bias,
                                                     ushort* __restrict__ q_ws,
                                                     ushort* __restrict__ k_ws,
                                                     ushort* __restrict__ v_tmp) {
  __shared__ ushort As[128 * 64];
  __shared__ ushort Bs[2][128 * 64];
  const int tid = threadIdx.x;
  const int wave = tid >> 6, lane = tid & 63;
  const int xcd = blockIdx.x & 7, loc = blockIdx.x >> 3;  // 768 = 8 * 96
  const int m0 = ((xcd >> 1) * 8 + (loc & 7)) * 128;      // 4 patches x 8 m-tiles
  const int n0 = ((xcd & 1) * 12 + (loc >> 3)) * 128;     // 2 patches x 12 n-tiles
  const int wr = (wave >> 1) * 64, wc = (wave & 1) * 64;
  const int l15 = lane & 15, lg = lane >> 4;
  const int swz = (l15 & 7) << 3;
  const int arow = wave * 32 + lg;
  const int akcol = l15 * 4;
  f32x4 acc[4][4] = {};
  float4 areg[8];

  auto a_issue = [&](int kt) {
#pragma unroll
    for (int c = 0; c < 8; ++c)
      areg[c] = *(const float4*)&X[(size_t)(m0 + arow + c * 4) * 1024 + kt * 64 + akcol];
  };
  auto a_write = [&]() {
#pragma unroll
    for (int c = 0; c < 8; ++c) {
      int row = arow + c * 4;
      unsigned p0, p1;
      asm("v_cvt_pk_bf16_f32 %0, %1, %2" : "=v"(p0) : "v"(areg[c].x), "v"(areg[c].y));
      asm("v_cvt_pk_bf16_f32 %0, %1, %2" : "=v"(p1) : "v"(areg[c].z), "v"(areg[c].w));
      *(uint2*)&As[row * 64 + (akcol ^ ((row & 7) << 3))] = make_uint2(p0, p1);
    }
  };
  auto stageB = [&](int kt, int buf) {
#pragma unroll
    for (int c = 0; c < 4; ++c) {
      int offB = wave * 4096 + c * 1024 + lane * 16;
      int row = offB >> 7, colB = offB & 127;
      gload_lds16((const char*)Bt + (size_t)(n0 + row) * 2048 + kt * 128 + colB,
                  (char*)Bs[buf] + wave * 4096 + c * 1024);
    }
  };

  // prologue: A(0) -> regs -> LDS; B(0) -> LDS; A(1) in flight
  a_issue(0);
  stageB(0, 0);
  a_write();                     // compiler inserts the counted vmcnt wait for areg
  a_issue(1);
  asm volatile("s_waitcnt vmcnt(8) lgkmcnt(0)" ::: "memory");  // B(0) landed; A(1) flying
  __builtin_amdgcn_s_barrier();

#pragma unroll 1
  for (int kt = 0; kt < 16; ++kt) {
    const int cur = kt & 1;
    if (kt < 15) stageB(kt + 1, cur ^ 1);
#pragma unroll
    for (int kc = 0; kc < 2; ++kc) {
      bf16x8 af[4], bfr[4];
#pragma unroll
      for (int i = 0; i < 4; ++i)
        af[i] = *(const bf16x8*)&As[(wr + i * 16 + l15) * 64 + ((kc * 32 + lg * 8) ^ swz)];
#pragma unroll
      for (int j = 0; j < 4; ++j)
        bfr[j] = *(const bf16x8*)&Bs[cur][(wc + j * 16 + l15) * 64 + ((kc * 32 + lg * 8) ^ swz)];
#pragma unroll
      for (int i = 0; i < 4; ++i)
#pragma unroll
        for (int j = 0; j < 4; ++j)
          acc[i][j] = __builtin_amdgcn_mfma_f32_16x16x32_bf16(af[i], bfr[j], acc[i][j], 0, 0, 0);
    }
    // mid barrier: LDS reads done, NO vmcnt drain (stageB(kt+1) stays in flight)
    asm volatile("s_waitcnt lgkmcnt(0)" ::: "memory");
    __builtin_amdgcn_s_barrier();
    if (kt < 15) {
      a_write();                // A(kt+1) -> As (all waves past barrier)
      if (kt < 14) a_issue(kt + 2);   // long-latency fp32 prefetch
      // force own stageB(kt+1) complete; areg(kt+2) (8 loads) stays airborne
      if (kt < 14) asm volatile("s_waitcnt vmcnt(8) lgkmcnt(0)" ::: "memory");
      else         asm volatile("s_waitcnt vmcnt(0) lgkmcnt(0)" ::: "memory");
      __builtin_amdgcn_s_barrier();   // publish As(kt+1) + Bs(kt+1)
    }
  }

  // epilogue: scatter q (exp2-scaled) / k (swizzled) / v (contiguous [bh][s][d])
#pragma unroll
  for (int j = 0; j < 4; ++j) {
    int col = n0 + wc + j * 16 + l15;
    float bv = bias[col];
    int sec = col >> 10;
    int within = col & 1023;
    int head = within >> 6, d = within & 63;
#pragma unroll
    for (int i = 0; i < 4; ++i) {
#pragma unroll
      for (int r = 0; r < 4; ++r) {
        int row = m0 + wr + i * 16 + lg * 4 + r;
        int b = row >> 11, s = row & 2047;
        float val = acc[i][j][r] + bv;
        size_t hb = ((size_t)(b * NH + head) * SEQ + s) * HD;
        if (sec == 0)      q_ws[hb + d] = f2bf(val * 0.1803368801f);  // log2(e)/8
        else if (sec == 1) k_ws[hb + (d ^ ((s & 7) << 3))] = f2bf(val);
        else               v_tmp[hb + d] = f2bf(val);
      }
    }
  }
}

// ---------------- flash attention (causal), paired mirrored Q-tiles ----------------
// Half-blocks: 2 waves per block handle 32 q-rows (h*32..h*32+31) of the pair
// (qtA, qtB) -> grid 1024 = 4 blocks/CU = 4 independent barrier domains.
// Same math as R12; hoisted K/V frags, pi-slot P/V, 1 barrier/kt, setprio.
__global__ __launch_bounds__(128) void k_attn(const ushort* __restrict__ q_ws,
                                              const ushort* __restrict__ k_ws,
                                              const ushort* __restrict__ v_ws,
                                              ushort* __restrict__ a_ws) {
  __shared__ ushort Ks[2][64 * 64];
  __shared__ ushort Vs[2][64 * 64];     // [d][slot], pi+XOR pre-applied in global
  __shared__ ushort Ps[2][2][16 * 64];  // per-wave, per-tile P buffer ([q][slot])
  const int bid = blockIdx.x;
  const int xcd = bid & 7, idx = bid >> 3;       // idx in [0,128)
  const int bh = xcd * 4 + (idx >> 5);           // 4 heads per XCD
  const int rem = idx & 31;
  const int p = rem & 15, h = rem >> 4;          // pair index, row-half
  const int qtA = 31 - p, qtB = p;      // qtB < qtA always (p in [0,16))
  const int tid = threadIdx.x, wave = tid >> 6, lane = tid & 63;
  const int w4 = h * 2 + wave;          // 16-row group index within the 64-row tile
  const int l15 = lane & 15, lg = lane >> 4;
  const int swz = (l15 & 7) << 3;       // element-index XOR for row=l15 reads
  const ushort* qp = q_ws + (size_t)bh * SEQ * HD;
  const ushort* kp = k_ws + (size_t)bh * SEQ * HD;
  const ushort* vp = v_ws + (size_t)bh * HD * SEQ;

  bf16x8 qfA[2], qfB[2];
  {
    int qrA = qtA * 64 + w4 * 16 + l15;
    int qrB = qtB * 64 + w4 * 16 + l15;
    qfA[0] = *(const bf16x8*)&qp[(size_t)qrA * HD + lg * 8];
    qfA[1] = *(const bf16x8*)&qp[(size_t)qrA * HD + 32 + lg * 8];
    qfB[0] = *(const bf16x8*)&qp[(size_t)qrB * HD + lg * 8];
    qfB[1] = *(const bf16x8*)&qp[(size_t)qrB * HD + 32 + lg * 8];
  }
  f32x4 oA[4] = {}, oB[4] = {};
  float mA[4] = {-INFINITY, -INFINITY, -INFINITY, -INFINITY};
  float mB[4] = {-INFINITY, -INFINITY, -INFINITY, -INFINITY};
  float lA[4] = {0.f, 0.f, 0.f, 0.f}, lB[4] = {0.f, 0.f, 0.f, 0.f};
  bf16x8 kf[2][4], vf[2][4];            // hoisted per-kt fragments

  // 2 waves: each stages 4 K-gloads + 4 V-gloads (8KB K + 8KB V per tile)
  auto stage = [&](int kt, int buf) {
#pragma unroll
    for (int c = 0; c < 4; ++c) {
      int offB = wave * 4096 + c * 1024 + lane * 16;
      gload_lds16((const char*)kp + (size_t)kt * 8192 + offB,
                  (char*)Ks[buf] + offB);
      int d = offB >> 7, keyB = offB & 127;
      gload_lds16((const char*)vp + (size_t)d * (SEQ * 2) + (size_t)kt * 128 + keyB,
                  (char*)Vs[buf] + offB);
    }
  };

  auto tile_step = [&](const bf16x8* qf, f32x4* o, float* m_r, float* l_r,
                       ushort* Pw, bool diag) {
    f32x4 sc[4] = {};
    __builtin_amdgcn_s_setprio(1);
#pragma unroll
    for (int kc = 0; kc < 2; ++kc)
#pragma unroll
      for (int f = 0; f < 4; ++f) {
        if (diag && f > w4) continue;  // fully-masked fragment
        sc[f] = __builtin_amdgcn_mfma_f32_16x16x32_bf16(qf[kc], kf[kc][f], sc[f], 0, 0, 0);
      }
    __builtin_amdgcn_s_setprio(0);
    if (diag) {
#pragma unroll
      for (int f = 0; f < 4; ++f) {
        int key_rel = f * 16 + l15;
#pragma unroll
        for (int r = 0; r < 4; ++r) {
          int q_rel = w4 * 16 + lg * 4 + r;
          if (key_rel > q_rel) sc[f][r] = -1e30f;
        }
      }
    }
    // lazy row-max: lane-local check, full reduce+rescale only when vote fires
    float pm[4];
#pragma unroll
    for (int r = 0; r < 4; ++r)
      pm[r] = fmaxf(fmaxf(sc[0][r], sc[1][r]), fmaxf(sc[2][r], sc[3][r]));
    bool need = false;
#pragma unroll
    for (int r = 0; r < 4; ++r) need |= (pm[r] > m_r[r] + 8.f);
    if (__any(need)) {   // rare: first tile, then ~never (defer-max, THR=8)
#pragma unroll
      for (int r = 0; r < 4; ++r) {
        float full = red16_max(pm[r]);
        float mn = fmaxf(m_r[r], full);
        float al = fast_exp2(m_r[r] - mn);
        m_r[r] = mn;
        l_r[r] *= al;
#pragma unroll
        for (int df = 0; df < 4; ++df) o[df][r] *= al;
      }
    }
    // P = exp2(sc-m): lane's 4 f-values at CONSECUTIVE slots (pi-permute)
#pragma unroll
    for (int r = 0; r < 4; ++r) {
      int q = lg * 4 + r;
      float e0 = fast_exp2(sc[0][r] - m_r[r]);
      float e1 = fast_exp2(sc[1][r] - m_r[r]);
      float e2 = fast_exp2(sc[2][r] - m_r[r]);
      float e3 = fast_exp2(sc[3][r] - m_r[r]);
      l_r[r] += (e0 + e1) + (e2 + e3);
      unsigned p0, p1;
      asm("v_cvt_pk_bf16_f32 %0, %1, %2" : "=v"(p0) : "v"(e0), "v"(e1));
      asm("v_cvt_pk_bf16_f32 %0, %1, %2" : "=v"(p1) : "v"(e2), "v"(e3));
      *(uint2*)&Pw[q * 64 + ((l15 * 4) ^ ((q & 7) << 3))] = make_uint2(p0, p1);
    }
    __builtin_amdgcn_s_setprio(1);
#pragma unroll
    for (int kc = 0; kc < 2; ++kc) {
      bf16x8 pf = *(const bf16x8*)&Pw[l15 * 64 + ((kc * 32 + lg * 8) ^ swz)];
#pragma unroll
      for (int df = 0; df < 4; ++df)
        o[df] = __builtin_amdgcn_mfma_f32_16x16x32_bf16(pf, vf[kc][df], o[df], 0, 0, 0);
    }
    __builtin_amdgcn_s_setprio(0);
  };

  stage(0, 0);
  asm volatile("s_waitcnt vmcnt(0)" ::: "memory");
  __syncthreads();

  for (int kt = 0; kt <= qtA; ++kt) {
    const int cur = kt & 1;
    if (kt < qtA) stage(kt + 1, cur ^ 1);   // buf[cur^1] readers synced at kt-1 barrier
    // hoisted fragment loads (shared by both tiles)
#pragma unroll
    for (int kc = 0; kc < 2; ++kc)
#pragma unroll
      for (int f = 0; f < 4; ++f) {
        kf[kc][f] = *(const bf16x8*)&Ks[cur][(f * 16 + l15) * 64 + ((kc * 32 + lg * 8) ^ swz)];
        vf[kc][f] = *(const bf16x8*)&Vs[cur][(f * 16 + l15) * 64 + ((kc * 32 + lg * 8) ^ swz)];
      }
    tile_step(qfA, oA, mA, lA, Ps[wave][0], kt == qtA);
    if (kt <= qtB)
      tile_step(qfB, oB, mB, lB, Ps[wave][1], kt == qtB);
    asm volatile("s_waitcnt vmcnt(0)" ::: "memory");  // stage(kt+1) landed
    __builtin_amdgcn_s_barrier();
  }

  int b = bh >> 4, head = bh & 15;
  // a_ws stored K-block swizzled (it is the A operand of k_gemm_proj)
  auto epilogue = [&](f32x4* o, float* l_r, int qt) {
#pragma unroll
    for (int r = 0; r < 4; ++r) {
      float inv = 1.0f / red16_sum(l_r[r]);
      int s = qt * 64 + w4 * 16 + lg * 4 + r;
#pragma unroll
      for (int df = 0; df < 4; ++df) {
        int col = head * 64 + ((df * 16 + l15) ^ ((s & 7) << 3));
        a_ws[((size_t)(b * SEQ + s)) * NXC + col] = f2bf(o[df][r] * inv);
      }
    }
  };
  epilogue(oA, lA, qtA);
  epilogue(oB, lB, qtB);
}

// ---------------- out-proj GEMM: out = A * Wt^T + b (fp32 out) ----------------
__global__ __launch_bounds__(256) void k_gemm_proj(const ushort* __restrict__ A,
                                                   const ushort* __restrict__ Bt,
                                                   const float* __restrict__ bias,
                                                   float* __restrict__ out) {
  __shared__ ushort As[2][128 * 64];
  __shared__ ushort Bs[2][128 * 64];
  const int tid = threadIdx.x;
  const int wave = tid >> 6, lane = tid & 63;
  const int xcd = blockIdx.x & 7, loc = blockIdx.x >> 3;  // 256 = 8 * 32
  const int m0 = ((xcd >> 1) * 8 + (loc & 7)) * 128;
  const int n0 = ((xcd & 1) * 4 + (loc >> 3)) * 128;
  const int wr = (wave >> 1) * 64, wc = (wave & 1) * 64;
  const int l15 = lane & 15, lg = lane >> 4;
  const int swz = (l15 & 7) << 3;
  f32x4 acc[4][4] = {};

  auto stage = [&](int k0, int buf) {
#pragma unroll
    for (int c = 0; c < 4; ++c) {
      int offB = wave * 4096 + c * 1024 + lane * 16;
      int row = offB >> 7, colB = offB & 127;
      gload_lds16((const char*)A + (size_t)(m0 + row) * 2048 + k0 * 2 + colB,
                  (char*)As[buf] + wave * 4096 + c * 1024);
      gload_lds16((const char*)Bt + (size_t)(n0 + row) * 2048 + k0 * 2 + colB,
                  (char*)Bs[buf] + wave * 4096 + c * 1024);
    }
  };

  stage(0, 0);
  asm volatile("s_waitcnt vmcnt(0)" ::: "memory");
  __syncthreads();

  for (int kt = 0; kt < 16; ++kt) {
    const int cur = kt & 1;
    if (kt < 15) stage((kt + 1) * 64, cur ^ 1);
#pragma unroll
    for (int kc = 0; kc < 2; ++kc) {
      bf16x8 af[4], bfr[4];
#pragma unroll
      for (int i = 0; i < 4; ++i)
        af[i] = *(const bf16x8*)&As[cur][(wr + i * 16 + l15) * 64 + ((kc * 32 + lg * 8) ^ swz)];
#pragma unroll
      for (int j = 0; j < 4; ++j)
        bfr[j] = *(const bf16x8*)&Bs[cur][(wc + j * 16 + l15) * 64 + ((kc * 32 + lg * 8) ^ swz)];
#pragma unroll
      for (int i = 0; i < 4; ++i)
#pragma unroll
        for (int j = 0; j < 4; ++j)
          acc[i][j] = __builtin_amdgcn_mfma_f32_16x16x32_bf16(af[i], bfr[j], acc[i][j], 0, 0, 0);
    }
    asm volatile("s_waitcnt vmcnt(0)" ::: "memory");
    __syncthreads();
  }
#pragma unroll
  for (int j = 0; j < 4; ++j) {
    int col = n0 + wc + j * 16 + l15;
    float bv = bias[col];
#pragma unroll
    for (int i = 0; i < 4; ++i) {
#pragma unroll
      for (int r = 0; r < 4; ++r) {
        int row = m0 + wr + i * 16 + lg * 4 + r;
        out[(size_t)row * NXC + col] = acc[i][j][r] + bv;
      }
    }
  }
}

extern "C" void kernel_launch(void* const* d_in, const int* in_sizes, int n_in,
                              void* d_out, int out_size, void* d_ws, size_t ws_size,
                              hipStream_t stream) {
  const float* hs       = (const float*)d_in[0];
  const float* c_attn_w = (const float*)d_in[1];
  const float* c_attn_b = (const float*)d_in[2];
  const float* c_proj_w = (const float*)d_in[3];
  const float* c_proj_b = (const float*)d_in[4];
  char* ws = (char*)d_ws;
  const size_t MB = 1 << 20;
  ushort* Wt_attn = (ushort*)(ws + 8 * MB);   // [3072][1024], K-block swizzled
  ushort* Wt_proj = (ushort*)(ws + 14 * MB);  // [1024][1024], K-block swizzled
  ushort* q_ws    = (ushort*)(ws + 16 * MB);  // [b][h][s][d], exp2-scaled
  ushort* k_ws    = (ushort*)(ws + 24 * MB);  // [b][h][s][d], d pre-swizzled
  ushort* v_ws    = (ushort*)(ws + 32 * MB);  // [b][h][d][slot], pi+XOR layout
  ushort* a_ws    = (ushort*)(ws + 40 * MB);  // [4096][1024] K-block swizzled; also v_tmp
  ushort* v_tmp   = a_ws;

  k_transpose_w<<<dim3(96, 32), 256, 0, stream>>>(c_attn_w, Wt_attn, 1024, 3072);
  k_transpose_w<<<dim3(32, 32), 256, 0, stream>>>(c_proj_w, Wt_proj, 1024, 1024);
  k_gemm_qkv<<<768, 256, 0, stream>>>(hs, Wt_attn, c_attn_b, q_ws, k_ws, v_tmp);
  k_transpose_v<<<dim3(32, 2, 32), 256, 0, stream>>>(v_tmp, v_ws);
  k_attn<<<1024, 128, 0, stream>>>(q_ws, k_ws, v_ws, a_ws);
  k_gemm_proj<<<256, 256, 0, stream>>>(a_ws, Wt_proj, c_proj_b, (float*)d_out);
}

// Round 16
// 123.291 us; speedup vs baseline: 1.0185x; 1.0185x over previous
//
#include <hip/hip_runtime.h>
#include <hip/hip_bf16.h>
#include <cmath>

typedef __attribute__((ext_vector_type(8))) short bf16x8;
typedef __attribute__((ext_vector_type(4))) float f32x4;

#define NXC 1024
#define NH 16
#define HD 64
#define BATCH 2
#define SEQ 2048
#define TOK (BATCH * SEQ)

// fp32 -> bf16 RNE via HW cvt (1 VALU op; same-src so half order is irrelevant)
__device__ __forceinline__ ushort f2bf(float f) {
  unsigned u;
  asm("v_cvt_pk_bf16_f32 %0, %1, %2" : "=v"(u) : "v"(f), "v"(f));
  return (ushort)u;
}

__device__ __forceinline__ void gload_lds16(const void* g, void* lds) {
  __builtin_amdgcn_global_load_lds(
      (const __attribute__((address_space(1))) void*)g,
      (__attribute__((address_space(3))) void*)lds, 16, 0, 0);
}

__device__ __forceinline__ float fast_exp2(float x) {
  float r;
  asm("v_exp_f32 %0, %1" : "=v"(r) : "v"(x));
  return r;
}

template <int CTRL>
__device__ __forceinline__ float dpp_mov(float x) {
  return __builtin_bit_cast(
      float, __builtin_amdgcn_mov_dpp(__builtin_bit_cast(int, x), CTRL, 0xF, 0xF, true));
}
// reduce across the 16 contiguous lanes of a DPP row (row_ror 1,2,4,8)
__device__ __forceinline__ float red16_max(float x) {
  x = fmaxf(x, dpp_mov<0x121>(x));
  x = fmaxf(x, dpp_mov<0x122>(x));
  x = fmaxf(x, dpp_mov<0x124>(x));
  x = fmaxf(x, dpp_mov<0x128>(x));
  return x;
}
__device__ __forceinline__ float red16_sum(float x) {
  x += dpp_mov<0x121>(x);
  x += dpp_mov<0x122>(x);
  x += dpp_mov<0x124>(x);
  x += dpp_mov<0x128>(x);
  return x;
}

// ---------------- W [K][N] fp32 -> Wt [N][K] bf16, K-block swizzled ----------------
__global__ __launch_bounds__(256) void k_transpose_w(const float* __restrict__ in,
                                                     ushort* __restrict__ out,
                                                     int Kd, int Nd) {
  __shared__ float t[32][33];
  int n0 = blockIdx.x * 32, k0 = blockIdx.y * 32;
  int tx = threadIdx.x & 31, ty = threadIdx.x >> 5;
#pragma unroll
  for (int r = 0; r < 4; ++r)
    t[tx][ty + r * 8] = in[(size_t)(k0 + ty + r * 8) * Nd + n0 + tx];
  __syncthreads();
  int nl = threadIdx.x >> 3, kq = (threadIdx.x & 7) * 4;
  ushort4 o;
  o.x = f2bf(t[nl][kq + 0]);
  o.y = f2bf(t[nl][kq + 1]);
  o.z = f2bf(t[nl][kq + 2]);
  o.w = f2bf(t[nl][kq + 3]);
  int row = n0 + nl, kk = k0 + kq;
  size_t dst = (size_t)row * Kd + (kk & ~63) + ((kk & 63) ^ ((row & 7) << 3));
  *(ushort4*)&out[dst] = o;
}

// ---------- V [b][h][s][d] -> [b][h][d][slot] (pi-permute + XOR swizzle) ----------
// slot(s,d) = ((s&15)*4 + ((s>>4)&3)) ^ ((d&7)<<3), per 64-key tile.
__global__ __launch_bounds__(256) void k_transpose_v(const ushort* __restrict__ in,
                                                     ushort* __restrict__ out) {
  __shared__ ushort t[64][33];          // [s_local][d_local]
  int bh = blockIdx.z;
  int s0 = blockIdx.x * 64, d0 = blockIdx.y * 32;
  const ushort* ip = in + (size_t)bh * SEQ * HD;
  ushort* op = out + (size_t)bh * HD * SEQ;
  int dl_in = threadIdx.x & 31, sl_in = threadIdx.x >> 5;  // 8 s-rows per pass
#pragma unroll
  for (int m = 0; m < 8; ++m)
    t[sl_in + m * 8][dl_in] = ip[(size_t)(s0 + sl_in + m * 8) * HD + d0 + dl_in];
  __syncthreads();
  int dl = threadIdx.x >> 3;            // 0..31
  int kp = threadIdx.x & 7;             // 0..7 -> two k values
#pragma unroll
  for (int kk = 0; kk < 2; ++kk) {
    int k = kp * 2 + kk;                // 0..15
    ushort4 o;
    o.x = t[k][dl]; o.y = t[k + 16][dl]; o.z = t[k + 32][dl]; o.w = t[k + 48][dl];
    int slot = (4 * k) ^ ((dl & 7) << 3);
    *(ushort4*)&op[(size_t)(d0 + dl) * SEQ + s0 + slot] = o;
  }
}

// ---------------- QKV GEMM (fused fp32->bf16 on A): C = X * Wt^T + b ----------------
// Mid-iteration barrier no longer drains vmcnt: stageB(kt+1) stays in flight
// through the a_write phase; end barrier uses COUNTED vmcnt(8) (areg prefetch
// stays airborne). No wave ever stalls mid-iteration on L2.
__global__ __launch_bounds__(256, 3) void k_gemm_qkv(const float* __restrict__ X,
                                                     const ushort* __restrict__ Bt,
                                                     const float* __restrict__ bias,
                                                     ushort* __restrict__ q_ws,
                                                     ushort* __restrict__ k_ws,
                                                     ushort* __restrict__ v_tmp) {
  __shared__ ushort As[128 * 64];
  __shared__ ushort Bs[2][128 * 64];
  const int tid = threadIdx.x;
  const int wave = tid >> 6, lane = tid & 63;
  const int xcd = blockIdx.x & 7, loc = blockIdx.x >> 3;  // 768 = 8 * 96
  const int m0 = ((xcd >> 1) * 8 + (loc & 7)) * 128;      // 4 patches x 8 m-tiles
  const int n0 = ((xcd & 1) * 12 + (loc >> 3)) * 128;     // 2 patches x 12 n-tiles
  const int wr = (wave >> 1) * 64, wc = (wave & 1) * 64;
  const int l15 = lane & 15, lg = lane >> 4;
  const int swz = (l15 & 7) << 3;
  const int arow = wave * 32 + lg;
  const int akcol = l15 * 4;
  f32x4 acc[4][4] = {};
  float4 areg[8];

  auto a_issue = [&](int kt) {
#pragma unroll
    for (int c = 0; c < 8; ++c)
      areg[c] = *(const float4*)&X[(size_t)(m0 + arow + c * 4) * 1024 + kt * 64 + akcol];
  };
  auto a_write = [&]() {
#pragma unroll
    for (int c = 0; c < 8; ++c) {
      int row = arow + c * 4;
      unsigned p0, p1;
      asm("v_cvt_pk_bf16_f32 %0, %1, %2" : "=v"(p0) : "v"(areg[c].x), "v"(areg[c].y));
      asm("v_cvt_pk_bf16_f32 %0, %1, %2" : "=v"(p1) : "v"(areg[c].z), "v"(areg[c].w));
      *(uint2*)&As[row * 64 + (akcol ^ ((row & 7) << 3))] = make_uint2(p0, p1);
    }
  };
  auto stageB = [&](int kt, int buf) {
#pragma unroll
    for (int c = 0; c < 4; ++c) {
      int offB = wave * 4096 + c * 1024 + lane * 16;
      int row = offB >> 7, colB = offB & 127;
      gload_lds16((const char*)Bt + (size_t)(n0 + row) * 2048 + kt * 128 + colB,
                  (char*)Bs[buf] + wave * 4096 + c * 1024);
    }
  };

  // prologue: A(0) -> regs -> LDS; B(0) -> LDS; A(1) in flight
  a_issue(0);
  stageB(0, 0);
  a_write();                     // compiler inserts the counted vmcnt wait for areg
  a_issue(1);
  asm volatile("s_waitcnt vmcnt(8) lgkmcnt(0)" ::: "memory");  // B(0) landed; A(1) flying
  __builtin_amdgcn_s_barrier();

#pragma unroll 1
  for (int kt = 0; kt < 16; ++kt) {
    const int cur = kt & 1;
    if (kt < 15) stageB(kt + 1, cur ^ 1);
#pragma unroll
    for (int kc = 0; kc < 2; ++kc) {
      bf16x8 af[4], bfr[4];
#pragma unroll
      for (int i = 0; i < 4; ++i)
        af[i] = *(const bf16x8*)&As[(wr + i * 16 + l15) * 64 + ((kc * 32 + lg * 8) ^ swz)];
#pragma unroll
      for (int j = 0; j < 4; ++j)
        bfr[j] = *(const bf16x8*)&Bs[cur][(wc + j * 16 + l15) * 64 + ((kc * 32 + lg * 8) ^ swz)];
#pragma unroll
      for (int i = 0; i < 4; ++i)
#pragma unroll
        for (int j = 0; j < 4; ++j)
          acc[i][j] = __builtin_amdgcn_mfma_f32_16x16x32_bf16(af[i], bfr[j], acc[i][j], 0, 0, 0);
    }
    // mid barrier: LDS reads done, NO vmcnt drain (stageB(kt+1) stays in flight)
    asm volatile("s_waitcnt lgkmcnt(0)" ::: "memory");
    __builtin_amdgcn_s_barrier();
    if (kt < 15) {
      a_write();                // A(kt+1) -> As (all waves past barrier)
      if (kt < 14) a_issue(kt + 2);   // long-latency fp32 prefetch
      // force own stageB(kt+1) complete; areg(kt+2) (8 loads) stays airborne
      if (kt < 14) asm volatile("s_waitcnt vmcnt(8) lgkmcnt(0)" ::: "memory");
      else         asm volatile("s_waitcnt vmcnt(0) lgkmcnt(0)" ::: "memory");
      __builtin_amdgcn_s_barrier();   // publish As(kt+1) + Bs(kt+1)
    }
  }

  // epilogue: scatter q (exp2-scaled) / k (swizzled) / v (contiguous [bh][s][d])
#pragma unroll
  for (int j = 0; j < 4; ++j) {
    int col = n0 + wc + j * 16 + l15;
    float bv = bias[col];
    int sec = col >> 10;
    int within = col & 1023;
    int head = within >> 6, d = within & 63;
#pragma unroll
    for (int i = 0; i < 4; ++i) {
#pragma unroll
      for (int r = 0; r < 4; ++r) {
        int row = m0 + wr + i * 16 + lg * 4 + r;
        int b = row >> 11, s = row & 2047;
        float val = acc[i][j][r] + bv;
        size_t hb = ((size_t)(b * NH + head) * SEQ + s) * HD;
        if (sec == 0)      q_ws[hb + d] = f2bf(val * 0.1803368801f);  // log2(e)/8
        else if (sec == 1) k_ws[hb + (d ^ ((s & 7) << 3))] = f2bf(val);
        else               v_tmp[hb + d] = f2bf(val);
      }
    }
  }
}

// ---------------- flash attention (causal), paired mirrored Q-tiles ----------------
// R12 version (validated local optimum): hoisted K/V register fragments, pi-slot
// P/V layout, single barrier per kt, setprio on MFMA, XCD-affine bh mapping.
__global__ __launch_bounds__(256) void k_attn(const ushort* __restrict__ q_ws,
                                              const ushort* __restrict__ k_ws,
                                              const ushort* __restrict__ v_ws,
                                              ushort* __restrict__ a_ws) {
  __shared__ ushort Ks[2][64 * 64];
  __shared__ ushort Vs[2][64 * 64];     // [d][slot], pi+XOR pre-applied in global
  __shared__ ushort Ps[4][2][16 * 64];  // per-wave, per-tile P buffer ([q][slot])
  const int bid = blockIdx.x;
  const int xcd = bid & 7, idx = bid >> 3;       // idx in [0,64)
  const int bh = xcd * 4 + (idx >> 4);           // 4 heads per XCD
  const int p = idx & 15;
  const int qtA = 31 - p, qtB = p;      // qtB < qtA always (p in [0,16))
  const int tid = threadIdx.x, wave = tid >> 6, lane = tid & 63;
  const int l15 = lane & 15, lg = lane >> 4;
  const int swz = (l15 & 7) << 3;       // element-index XOR for row=l15 reads
  const ushort* qp = q_ws + (size_t)bh * SEQ * HD;
  const ushort* kp = k_ws + (size_t)bh * SEQ * HD;
  const ushort* vp = v_ws + (size_t)bh * HD * SEQ;

  bf16x8 qfA[2], qfB[2];
  {
    int qrA = qtA * 64 + wave * 16 + l15;
    int qrB = qtB * 64 + wave * 16 + l15;
    qfA[0] = *(const bf16x8*)&qp[(size_t)qrA * HD + lg * 8];
    qfA[1] = *(const bf16x8*)&qp[(size_t)qrA * HD + 32 + lg * 8];
    qfB[0] = *(const bf16x8*)&qp[(size_t)qrB * HD + lg * 8];
    qfB[1] = *(const bf16x8*)&qp[(size_t)qrB * HD + 32 + lg * 8];
  }
  f32x4 oA[4] = {}, oB[4] = {};
  float mA[4] = {-INFINITY, -INFINITY, -INFINITY, -INFINITY};
  float mB[4] = {-INFINITY, -INFINITY, -INFINITY, -INFINITY};
  float lA[4] = {0.f, 0.f, 0.f, 0.f}, lB[4] = {0.f, 0.f, 0.f, 0.f};
  bf16x8 kf[2][4], vf[2][4];            // hoisted per-kt fragments

  auto stage = [&](int kt, int buf) {
#pragma unroll
    for (int c = 0; c < 2; ++c) {
      int offB = wave * 2048 + c * 1024 + lane * 16;
      gload_lds16((const char*)kp + (size_t)kt * 8192 + offB,
                  (char*)Ks[buf] + offB);
      int d = offB >> 7, keyB = offB & 127;
      gload_lds16((const char*)vp + (size_t)d * (SEQ * 2) + (size_t)kt * 128 + keyB,
                  (char*)Vs[buf] + offB);
    }
  };

  auto tile_step = [&](const bf16x8* qf, f32x4* o, float* m_r, float* l_r,
                       ushort* Pw, bool diag) {
    f32x4 sc[4] = {};
    __builtin_amdgcn_s_setprio(1);
#pragma unroll
    for (int kc = 0; kc < 2; ++kc)
#pragma unroll
      for (int f = 0; f < 4; ++f) {
        if (diag && f > wave) continue;  // fully-masked fragment
        sc[f] = __builtin_amdgcn_mfma_f32_16x16x32_bf16(qf[kc], kf[kc][f], sc[f], 0, 0, 0);
      }
    __builtin_amdgcn_s_setprio(0);
    if (diag) {
#pragma unroll
      for (int f = 0; f < 4; ++f) {
        int key_rel = f * 16 + l15;
#pragma unroll
        for (int r = 0; r < 4; ++r) {
          int q_rel = wave * 16 + lg * 4 + r;
          if (key_rel > q_rel) sc[f][r] = -1e30f;
        }
      }
    }
    // lazy row-max: lane-local check, full reduce+rescale only when vote fires
    float pm[4];
#pragma unroll
    for (int r = 0; r < 4; ++r)
      pm[r] = fmaxf(fmaxf(sc[0][r], sc[1][r]), fmaxf(sc[2][r], sc[3][r]));
    bool need = false;
#pragma unroll
    for (int r = 0; r < 4; ++r) need |= (pm[r] > m_r[r] + 8.f);
    if (__any(need)) {   // rare: first tile, then ~never (defer-max, THR=8)
#pragma unroll
      for (int r = 0; r < 4; ++r) {
        float full = red16_max(pm[r]);
        float mn = fmaxf(m_r[r], full);
        float al = fast_exp2(m_r[r] - mn);
        m_r[r] = mn;
        l_r[r] *= al;
#pragma unroll
        for (int df = 0; df < 4; ++df) o[df][r] *= al;
      }
    }
    // P = exp2(sc-m): lane's 4 f-values at CONSECUTIVE slots (pi-permute)
#pragma unroll
    for (int r = 0; r < 4; ++r) {
      int q = lg * 4 + r;
      float e0 = fast_exp2(sc[0][r] - m_r[r]);
      float e1 = fast_exp2(sc[1][r] - m_r[r]);
      float e2 = fast_exp2(sc[2][r] - m_r[r]);
      float e3 = fast_exp2(sc[3][r] - m_r[r]);
      l_r[r] += (e0 + e1) + (e2 + e3);
      unsigned p0, p1;
      asm("v_cvt_pk_bf16_f32 %0, %1, %2" : "=v"(p0) : "v"(e0), "v"(e1));
      asm("v_cvt_pk_bf16_f32 %0, %1, %2" : "=v"(p1) : "v"(e2), "v"(e3));
      *(uint2*)&Pw[q * 64 + ((l15 * 4) ^ ((q & 7) << 3))] = make_uint2(p0, p1);
    }
    __builtin_amdgcn_s_setprio(1);
#pragma unroll
    for (int kc = 0; kc < 2; ++kc) {
      bf16x8 pf = *(const bf16x8*)&Pw[l15 * 64 + ((kc * 32 + lg * 8) ^ swz)];
#pragma unroll
      for (int df = 0; df < 4; ++df)
        o[df] = __builtin_amdgcn_mfma_f32_16x16x32_bf16(pf, vf[kc][df], o[df], 0, 0, 0);
    }
    __builtin_amdgcn_s_setprio(0);
  };

  stage(0, 0);
  asm volatile("s_waitcnt vmcnt(0)" ::: "memory");
  __syncthreads();

  for (int kt = 0; kt <= qtA; ++kt) {
    const int cur = kt & 1;
    if (kt < qtA) stage(kt + 1, cur ^ 1);   // buf[cur^1] readers synced at kt-1 barrier
    // hoisted fragment loads (shared by both tiles)
#pragma unroll
    for (int kc = 0; kc < 2; ++kc)
#pragma unroll
      for (int f = 0; f < 4; ++f) {
        kf[kc][f] = *(const bf16x8*)&Ks[cur][(f * 16 + l15) * 64 + ((kc * 32 + lg * 8) ^ swz)];
        vf[kc][f] = *(const bf16x8*)&Vs[cur][(f * 16 + l15) * 64 + ((kc * 32 + lg * 8) ^ swz)];
      }
    tile_step(qfA, oA, mA, lA, Ps[wave][0], kt == qtA);
    if (kt <= qtB)
      tile_step(qfB, oB, mB, lB, Ps[wave][1], kt == qtB);
    asm volatile("s_waitcnt vmcnt(0)" ::: "memory");  // stage(kt+1) landed
    __builtin_amdgcn_s_barrier();
  }

  int b = bh >> 4, head = bh & 15;
  // a_ws stored K-block swizzled (it is the A operand of k_gemm_proj)
  auto epilogue = [&](f32x4* o, float* l_r, int qt) {
#pragma unroll
    for (int r = 0; r < 4; ++r) {
      float inv = 1.0f / red16_sum(l_r[r]);
      int s = qt * 64 + wave * 16 + lg * 4 + r;
#pragma unroll
      for (int df = 0; df < 4; ++df) {
        int col = head * 64 + ((df * 16 + l15) ^ ((s & 7) << 3));
        a_ws[((size_t)(b * SEQ + s)) * NXC + col] = f2bf(o[df][r] * inv);
      }
    }
  };
  epilogue(oA, lA, qtA);
  epilogue(oB, lB, qtB);
}

// ---------------- out-proj GEMM: out = A * Wt^T + b (fp32 out) ----------------
__global__ __launch_bounds__(256) void k_gemm_proj(const ushort* __restrict__ A,
                                                   const ushort* __restrict__ Bt,
                                                   const float* __restrict__ bias,
                                                   float* __restrict__ out) {
  __shared__ ushort As[2][128 * 64];
  __shared__ ushort Bs[2][128 * 64];
  const int tid = threadIdx.x;
  const int wave = tid >> 6, lane = tid & 63;
  const int xcd = blockIdx.x & 7, loc = blockIdx.x >> 3;  // 256 = 8 * 32
  const int m0 = ((xcd >> 1) * 8 + (loc & 7)) * 128;
  const int n0 = ((xcd & 1) * 4 + (loc >> 3)) * 128;
  const int wr = (wave >> 1) * 64, wc = (wave & 1) * 64;
  const int l15 = lane & 15, lg = lane >> 4;
  const int swz = (l15 & 7) << 3;
  f32x4 acc[4][4] = {};

  auto stage = [&](int k0, int buf) {
#pragma unroll
    for (int c = 0; c < 4; ++c) {
      int offB = wave * 4096 + c * 1024 + lane * 16;
      int row = offB >> 7, colB = offB & 127;
      gload_lds16((const char*)A + (size_t)(m0 + row) * 2048 + k0 * 2 + colB,
                  (char*)As[buf] + wave * 4096 + c * 1024);
      gload_lds16((const char*)Bt + (size_t)(n0 + row) * 2048 + k0 * 2 + colB,
                  (char*)Bs[buf] + wave * 4096 + c * 1024);
    }
  };

  stage(0, 0);
  asm volatile("s_waitcnt vmcnt(0)" ::: "memory");
  __syncthreads();

  for (int kt = 0; kt < 16; ++kt) {
    const int cur = kt & 1;
    if (kt < 15) stage((kt + 1) * 64, cur ^ 1);
#pragma unroll
    for (int kc = 0; kc < 2; ++kc) {
      bf16x8 af[4], bfr[4];
#pragma unroll
      for (int i = 0; i < 4; ++i)
        af[i] = *(const bf16x8*)&As[cur][(wr + i * 16 + l15) * 64 + ((kc * 32 + lg * 8) ^ swz)];
#pragma unroll
      for (int j = 0; j < 4; ++j)
        bfr[j] = *(const bf16x8*)&Bs[cur][(wc + j * 16 + l15) * 64 + ((kc * 32 + lg * 8) ^ swz)];
#pragma unroll
      for (int i = 0; i < 4; ++i)
#pragma unroll
        for (int j = 0; j < 4; ++j)
          acc[i][j] = __builtin_amdgcn_mfma_f32_16x16x32_bf16(af[i], bfr[j], acc[i][j], 0, 0, 0);
    }
    asm volatile("s_waitcnt vmcnt(0)" ::: "memory");
    __syncthreads();
  }
#pragma unroll
  for (int j = 0; j < 4; ++j) {
    int col = n0 + wc + j * 16 + l15;
    float bv = bias[col];
#pragma unroll
    for (int i = 0; i < 4; ++i) {
#pragma unroll
      for (int r = 0; r < 4; ++r) {
        int row = m0 + wr + i * 16 + lg * 4 + r;
        out[(size_t)row * NXC + col] = acc[i][j][r] + bv;
      }
    }
  }
}

extern "C" void kernel_launch(void* const* d_in, const int* in_sizes, int n_in,
                              void* d_out, int out_size, void* d_ws, size_t ws_size,
                              hipStream_t stream) {
  const float* hs       = (const float*)d_in[0];
  const float* c_attn_w = (const float*)d_in[1];
  const float* c_attn_b = (const float*)d_in[2];
  const float* c_proj_w = (const float*)d_in[3];
  const float* c_proj_b = (const float*)d_in[4];
  char* ws = (char*)d_ws;
  const size_t MB = 1 << 20;
  ushort* Wt_attn = (ushort*)(ws + 8 * MB);   // [3072][1024], K-block swizzled
  ushort* Wt_proj = (ushort*)(ws + 14 * MB);  // [1024][1024], K-block swizzled
  ushort* q_ws    = (ushort*)(ws + 16 * MB);  // [b][h][s][d], exp2-scaled
  ushort* k_ws    = (ushort*)(ws + 24 * MB);  // [b][h][s][d], d pre-swizzled
  ushort* v_ws    = (ushort*)(ws + 32 * MB);  // [b][h][d][slot], pi+XOR layout
  ushort* a_ws    = (ushort*)(ws + 40 * MB);  // [4096][1024] K-block swizzled; also v_tmp
  ushort* v_tmp   = a_ws;

  k_transpose_w<<<dim3(96, 32), 256, 0, stream>>>(c_attn_w, Wt_attn, 1024, 3072);
  k_transpose_w<<<dim3(32, 32), 256, 0, stream>>>(c_proj_w, Wt_proj, 1024, 1024);
  k_gemm_qkv<<<768, 256, 0, stream>>>(hs, Wt_attn, c_attn_b, q_ws, k_ws, v_tmp);
  k_transpose_v<<<dim3(32, 2, 32), 256, 0, stream>>>(v_tmp, v_ws);
  k_attn<<<512, 256, 0, stream>>>(q_ws, k_ws, v_ws, a_ws);
  k_gemm_proj<<<256, 256, 0, stream>>>(a_ws, Wt_proj, c_proj_b, (float*)d_out);
}